// Round 5
// baseline (102.310 us; speedup 1.0000x reference)
//
#include <hip/hip_runtime.h>
#include <hip/hip_bf16.h>
#include <math.h>

// M=100000 nodes, D=64, G=1024 graphs. batch sorted -> contiguous segments.
// out[g] = triu( sum_{m in seg g} a_m * x_m x_m^T ),  a = segment-softmax(x.w+b)
//        = triu( (diag(e) X_g)^T X_g ) / denom   with e_m = exp(imp_m) (no max
//          subtract needed: |imp| <~ 6 for this distribution; softmax is
//          shift-invariant so result is identical in exact arithmetic).

#define DDIM 64
#define NTRI 2080          // 64*65/2
#define CAP  1024          // LDS cache of exp(imp) (n ~ 98, max ~140)
#define TK   32            // K-tile (nodes per MFMA step)

typedef __bf16 bf16x8 __attribute__((ext_vector_type(8)));
typedef float  f32x4  __attribute__((ext_vector_type(4)));

__device__ __forceinline__ float dot_row_w(const float* __restrict__ row,
                                           const float* __restrict__ sW) {
    float d = 0.f;
#pragma unroll
    for (int k = 0; k < 16; ++k) {
        const float4 v = ((const float4*)row)[k];
        const float4 w = ((const float4*)sW)[k];
        d = fmaf(v.x, w.x, d); d = fmaf(v.y, w.y, d);
        d = fmaf(v.z, w.z, d); d = fmaf(v.w, w.w, d);
    }
    return d;
}

__device__ __forceinline__ unsigned pack_bf16(float a, float b) {
    __hip_bfloat162 h2 = __float22bfloat162_rn(make_float2(a, b)); // a->.x (low)
    return *reinterpret_cast<unsigned*>(&h2);
}

// ---------------- Kernel A: segment boundaries from sorted batch (tiny)
__global__ void __launch_bounds__(256)
bounds_kernel(const int* __restrict__ batch, int* __restrict__ seg_start, int M, int G)
{
    const int m = blockIdx.x * 256 + threadIdx.x;
    if (m >= M) return;
    const int b0 = batch[m];
    if (m == 0) {
        for (int g = 0; g <= b0; ++g) seg_start[g] = 0;
    } else {
        const int bp = batch[m - 1];
        for (int g = bp + 1; g <= b0; ++g) seg_start[g] = m;
    }
    if (m == M - 1) {
        for (int g = b0 + 1; g <= G; ++g) seg_start[g] = M;
    }
}

// ---------------- Kernel B: fused attention-softmax + MFMA second moment
__global__ void __launch_bounds__(256)
sop_kernel(const float* __restrict__ x,
           const float* __restrict__ att_w,
           const float* __restrict__ att_b,
           const int*   __restrict__ seg_start,
           float*       __restrict__ out)
{
    // Tiles stored TRANSPOSED: [feat 0..63][node 0..31] bf16, 16B chunks
    // XOR-swizzled (same scheme as verified R4 kernel).
    __shared__ unsigned short sT[2][2][DDIM * TK];   // [buf][A=0/B=1], 16 KiB
    __shared__ float sA[CAP];                        // e_m = exp(imp_m), UNnormalized
    __shared__ float sW[DDIM];
    __shared__ float sRed[8];

    const int g   = blockIdx.x;
    const int tid = threadIdx.x;
    const int s   = seg_start[g];
    const int n   = seg_start[g + 1] - s;
    float* og = out + (size_t)g * NTRI;

    if (n == 0) {                                // out poisoned -> write zeros
        for (int i = tid; i < NTRI; i += 256) og[i] = 0.f;
        return;
    }

    const float4* x4 = (const float4*)x;
    const int lane16 = tid & 15;
    const int grp16  = tid >> 4;

    // --- hoisted prefetch of tile 0 (in flight during phase 1) ---
    const int pp = tid & 15;          // staging: node pair p -> nodes 2p, 2p+1
    const int cc = tid >> 4;          // staging: float4 chunk (feats 4cc..4cc+3)
    float4 p0, p1;
    {
        const int m0 = 2 * pp;
        const float4 z = {0.f, 0.f, 0.f, 0.f};
        p0 = (m0     < n) ? x4[(size_t)(s + m0) * 16 + cc]     : z;
        p1 = (m0 + 1 < n) ? x4[(size_t)(s + m0 + 1) * 16 + cc] : z;
    }

    // --- phase 1: e_m = exp(x.w + b) into sA; block sum -> denom ---
    const float4 wv = ((const float4*)att_w)[lane16];
    const float  bb = att_b[0];
    if (tid < DDIM) sW[tid] = att_w[tid];

    float lsum = 0.f;
    for (int idx = grp16; idx < n; idx += 16) {
        const float4 v = x4[(size_t)(s + idx) * 16 + lane16];
        float d = fmaf(v.x, wv.x, fmaf(v.y, wv.y, fmaf(v.z, wv.z, v.w * wv.w)));
        d += __shfl_xor(d, 1, 16);
        d += __shfl_xor(d, 2, 16);
        d += __shfl_xor(d, 4, 16);
        d += __shfl_xor(d, 8, 16);
        if (lane16 == 0) {
            const float e = __expf(d + bb);
            if (idx < CAP) sA[idx] = e;
            lsum += e;
        }
    }
    const int wid = tid >> 6, lane = tid & 63;
#pragma unroll
    for (int off = 32; off > 0; off >>= 1) lsum += __shfl_down(lsum, off, 64);
    if (lane == 0) sRed[wid] = lsum;
    __syncthreads();                              // sA + sW + sRed visible
    if (tid == 0) sRed[4] = 1.0f / (sRed[0] + sRed[1] + sRed[2] + sRed[3]);
    // (sRed[4] read only at epilogue; >=1 tile barrier intervenes since n>=1)

    // --- phase 2: K-loop, mfma_f32_16x16x32_bf16, wave w owns C rows 16w..16w+15 ---
    const int il = lane & 15;
    const int qd = lane >> 4;                     // 0..3
    const int sw = qd ^ ((il >> 1) & 3);          // swizzled chunk pos
    const int offA = (16 * wid + il) * TK + (sw << 3);   // ushort offset
    const int offB = il * TK + (sw << 3);                // + jt*16*TK

    f32x4 acc[4];
#pragma unroll
    for (int jt = 0; jt < 4; ++jt) acc[jt] = (f32x4){0.f, 0.f, 0.f, 0.f};

    const int T = (n + TK - 1) / TK;

    for (int t = 0; t < T; ++t) {
        const int t0  = t * TK;
        const int cur = t & 1;
        unsigned* A32 = (unsigned*)sT[cur][0];
        unsigned* B32 = (unsigned*)sT[cur][1];

        // unnormalized weights e_m for this thread's node pair
        const int m0 = t0 + 2 * pp;
        float c0 = 0.f, c1 = 0.f;
        if (m0 < n)
            c0 = (m0 < CAP) ? sA[m0]
               : __expf(dot_row_w(x + (size_t)(s + m0) * DDIM, sW) + bb);
        if (m0 + 1 < n)
            c1 = (m0 + 1 < CAP) ? sA[m0 + 1]
               : __expf(dot_row_w(x + (size_t)(s + m0 + 1) * DDIM, sW) + bb);

        // stage transposed bf16 tiles (A = e-scaled, B = raw)
        const float* f0 = (const float*)&p0;
        const float* f1 = (const float*)&p1;
#pragma unroll
        for (int jf = 0; jf < 4; ++jf) {
            const int f   = 4 * cc + jf;
            const int pos = (pp >> 2) ^ ((f >> 1) & 3);
            const int ui  = f * (TK / 2) + (pos << 2) + (pp & 3);
            A32[ui] = pack_bf16(c0 * f0[jf], c1 * f1[jf]);
            B32[ui] = pack_bf16(f0[jf], f1[jf]);
        }

        if (t + 1 < T) {                // register prefetch of next tile
            const int m0n = (t + 1) * TK + 2 * pp;
            const float4 z = {0.f, 0.f, 0.f, 0.f};
            p0 = (m0n     < n) ? x4[(size_t)(s + m0n) * 16 + cc]     : z;
            p1 = (m0n + 1 < n) ? x4[(size_t)(s + m0n + 1) * 16 + cc] : z;
        }
        __syncthreads();                // single barrier per tile (double buffer)

        const unsigned short* As = sT[cur][0];
        const unsigned short* Bs = sT[cur][1];
        const bf16x8 av = *(const bf16x8*)(As + offA);
#pragma unroll
        for (int jt = 0; jt < 4; ++jt) {
            const bf16x8 bv = *(const bf16x8*)(Bs + offB + jt * 16 * TK);
            acc[jt] = __builtin_amdgcn_mfma_f32_16x16x32_bf16(av, bv, acc[jt], 0, 0, 0);
        }
    }

    // --- epilogue: scale by 1/denom; C/D layout col=lane&15, row=qd*4+reg ---
    const float invd = sRed[4];
    const int rbase = 16 * wid + qd * 4;
#pragma unroll
    for (int jt = 0; jt < 4; ++jt) {
        const int j = 16 * jt + il;
#pragma unroll
        for (int r = 0; r < 4; ++r) {
            const int i = rbase + r;
            if (j >= i) og[i * DDIM - (i * (i - 1)) / 2 + (j - i)] = acc[jt][r] * invd;
        }
    }
}

extern "C" void kernel_launch(void* const* d_in, const int* in_sizes, int n_in,
                              void* d_out, int out_size, void* d_ws, size_t ws_size,
                              hipStream_t stream) {
    const float* x     = (const float*)d_in[0];
    const float* att_w = (const float*)d_in[1];
    const float* att_b = (const float*)d_in[2];
    const int*   batch = (const int*)d_in[3];
    // d_in[4] = edge: dead code in reference
    float* out = (float*)d_out;

    const int M = in_sizes[0] / DDIM;
    const int G = out_size / NTRI;

    int* seg_start = (int*)d_ws;                          // (G+1) ints

    bounds_kernel<<<(M + 255) / 256, 256, 0, stream>>>(batch, seg_start, M, G);
    sop_kernel<<<G, 256, 0, stream>>>(x, att_w, att_b, seg_start, out);
}

// Round 6
// 90.771 us; speedup vs baseline: 1.1271x; 1.1271x over previous
//
#include <hip/hip_runtime.h>
#include <hip/hip_bf16.h>
#include <math.h>

// M=100000 nodes, D=64, G=1024 graphs. batch sorted -> contiguous segments.
// out[g] = triu( sum_{m in seg g} a_m * x_m x_m^T ),  a = segment-softmax(x.w+b)
//        = triu( (diag(e) X_g)^T X_g ) / denom,  e_m = exp(imp_m)  (shift-free:
//          |imp| <~ 6 here, far from fp32 exp overflow; softmax shift-invariant).
// Single pass: e_m computed from the staged registers themselves (width-16
// shuffle dot), so x is read from global exactly once.

#define DDIM 64
#define NTRI 2080          // 64*65/2
#define TK   32            // K-tile (nodes per MFMA step)

typedef __bf16 bf16x8 __attribute__((ext_vector_type(8)));
typedef float  f32x4  __attribute__((ext_vector_type(4)));

__device__ __forceinline__ unsigned pack_bf16(float a, float b) {
    __hip_bfloat162 h2 = __float22bfloat162_rn(make_float2(a, b)); // a -> low ushort
    return *reinterpret_cast<unsigned*>(&h2);
}

// ---------------- Kernel A: segment boundaries from sorted batch (tiny)
__global__ void __launch_bounds__(256)
bounds_kernel(const int* __restrict__ batch, int* __restrict__ seg_start, int M, int G)
{
    const int m = blockIdx.x * 256 + threadIdx.x;
    if (m >= M) return;
    const int b0 = batch[m];
    if (m == 0) {
        for (int g = 0; g <= b0; ++g) seg_start[g] = 0;
    } else {
        const int bp = batch[m - 1];
        for (int g = bp + 1; g <= b0; ++g) seg_start[g] = m;
    }
    if (m == M - 1) {
        for (int g = b0 + 1; g <= G; ++g) seg_start[g] = M;
    }
}

// ---------------- Kernel B: fully-fused single-pass softmax + MFMA second moment
__global__ void __launch_bounds__(256)
sop_kernel(const float* __restrict__ x,
           const float* __restrict__ att_w,
           const float* __restrict__ att_b,
           const int*   __restrict__ seg_start,
           float*       __restrict__ out)
{
    // Tiles TRANSPOSED [feat][node] bf16; dword-group swizzle:
    // group pos = (p>>2) ^ ((f>>2)&3)  (reader: sw = q ^ ((row>>2)&3)).
    __shared__ unsigned short sT[2][2][DDIM * TK];   // [buf][A=0/B=1], 16 KiB
    __shared__ float sRed[8];

    const int g   = blockIdx.x;
    const int tid = threadIdx.x;
    const int s   = seg_start[g];
    const int n   = seg_start[g + 1] - s;
    float* og = out + (size_t)g * NTRI;

    if (n == 0) {                                // out poisoned -> write zeros
        for (int i = tid; i < NTRI; i += 256) og[i] = 0.f;
        return;
    }

    const float4* x4 = (const float4*)x;
    const int wid  = tid >> 6;
    const int lane = tid & 63;
    const int c    = lane & 15;      // feature chunk (float4), == MFMA row il
    const int q    = lane >> 4;      // 0..3, == MFMA quad qd
    const int p    = 4 * wid + q;    // node-pair index 0..15 (nodes 2p, 2p+1)

    const float4 wv = ((const float4*)att_w)[c];
    const float  bb = att_b[0];

    // MFMA read offsets (ushort units)
    const int sw   = q ^ ((c >> 2) & 3);
    const int offA = (16 * wid + c) * TK + (sw << 3);
    const int offB = c * TK + (sw << 3);         // + jt*16*TK

    f32x4 acc[4];
#pragma unroll
    for (int jt = 0; jt < 4; ++jt) acc[jt] = (f32x4){0.f, 0.f, 0.f, 0.f};

    const int T = (n + TK - 1) / TK;
    float lsum = 0.f;                 // 16x-redundant running sum of e_m

    // prefetch tile 0
    float4 p0, p1;
    {
        const int m0 = 2 * p;
        const float4 z = {0.f, 0.f, 0.f, 0.f};
        p0 = (m0     < n) ? x4[(size_t)(s + m0) * 16 + c]     : z;
        p1 = (m0 + 1 < n) ? x4[(size_t)(s + m0 + 1) * 16 + c] : z;
    }

    for (int t = 0; t < T; ++t) {
        const int m0  = t * TK + 2 * p;
        const int cur = t & 1;

        // dot(x_m, w) via width-16 shuffle reduce; then e_m = exp(. + b)
        float d0 = fmaf(p0.x, wv.x, fmaf(p0.y, wv.y, fmaf(p0.z, wv.z, p0.w * wv.w)));
        float d1 = fmaf(p1.x, wv.x, fmaf(p1.y, wv.y, fmaf(p1.z, wv.z, p1.w * wv.w)));
#pragma unroll
        for (int mk = 1; mk < 16; mk <<= 1) {
            d0 += __shfl_xor(d0, mk, 16);
            d1 += __shfl_xor(d1, mk, 16);
        }
        float e0 = 0.f, e1 = 0.f;
        if (m0     < n) e0 = __expf(d0 + bb);
        if (m0 + 1 < n) e1 = __expf(d1 + bb);
        lsum += e0 + e1;

        // stage transposed bf16 tiles (A = e-scaled, B = raw)
        unsigned* A32 = (unsigned*)sT[cur][0];
        unsigned* B32 = (unsigned*)sT[cur][1];
        const float* f0 = (const float*)&p0;
        const float* f1 = (const float*)&p1;
#pragma unroll
        for (int jf = 0; jf < 4; ++jf) {
            const int ui = (4 * c + jf) * 16 + ((wid ^ (c & 3)) << 2) + q;
            A32[ui] = pack_bf16(e0 * f0[jf], e1 * f1[jf]);
            B32[ui] = pack_bf16(f0[jf], f1[jf]);
        }

        if (t + 1 < T) {               // register prefetch of next tile
            const int m0n = (t + 1) * TK + 2 * p;
            const float4 z = {0.f, 0.f, 0.f, 0.f};
            p0 = (m0n     < n) ? x4[(size_t)(s + m0n) * 16 + c]     : z;
            p1 = (m0n + 1 < n) ? x4[(size_t)(s + m0n + 1) * 16 + c] : z;
        }
        __syncthreads();               // single barrier per tile (double buffer)

        const unsigned short* As = sT[cur][0];
        const unsigned short* Bs = sT[cur][1];
        const bf16x8 av = *(const bf16x8*)(As + offA);
#pragma unroll
        for (int jt = 0; jt < 4; ++jt) {
            const bf16x8 bv = *(const bf16x8*)(Bs + offB + jt * 16 * TK);
            acc[jt] = __builtin_amdgcn_mfma_f32_16x16x32_bf16(av, bv, acc[jt], 0, 0, 0);
        }
    }

    // --- denom: wave reduce (16x overcount, exact /16) + cross-wave combine ---
#pragma unroll
    for (int off = 32; off > 0; off >>= 1) lsum += __shfl_down(lsum, off, 64);
    if (lane == 0) sRed[wid] = lsum;
    __syncthreads();
    if (tid == 0) sRed[4] = 16.0f / (sRed[0] + sRed[1] + sRed[2] + sRed[3]);
    __syncthreads();
    const float invd = sRed[4];

    // --- epilogue: C/D layout col=lane&15, row=q*4+reg -> triu scatter ---
    const int rbase = 16 * wid + q * 4;
#pragma unroll
    for (int jt = 0; jt < 4; ++jt) {
        const int j = 16 * jt + c;
#pragma unroll
        for (int r = 0; r < 4; ++r) {
            const int i = rbase + r;
            if (j >= i) og[i * DDIM - (i * (i - 1)) / 2 + (j - i)] = acc[jt][r] * invd;
        }
    }
}

extern "C" void kernel_launch(void* const* d_in, const int* in_sizes, int n_in,
                              void* d_out, int out_size, void* d_ws, size_t ws_size,
                              hipStream_t stream) {
    const float* x     = (const float*)d_in[0];
    const float* att_w = (const float*)d_in[1];
    const float* att_b = (const float*)d_in[2];
    const int*   batch = (const int*)d_in[3];
    // d_in[4] = edge: dead code in reference
    float* out = (float*)d_out;

    const int M = in_sizes[0] / DDIM;
    const int G = out_size / NTRI;

    int* seg_start = (int*)d_ws;                          // (G+1) ints

    bounds_kernel<<<(M + 255) / 256, 256, 0, stream>>>(batch, seg_start, M, G);
    sop_kernel<<<G, 256, 0, stream>>>(x, att_w, att_b, seg_start, out);
}